// Round 4
// baseline (379.441 us; speedup 1.0000x reference)
//
#include <hip/hip_runtime.h>

#define DEV __device__ __forceinline__

typedef short bf16x8 __attribute__((ext_vector_type(8)));
typedef float f32x4 __attribute__((ext_vector_type(4)));

constexpr int BATCH = 16384, T = 64, H = 14;
constexpr float NL2E  = -1.4426950408889634f;   // -log2(e)
constexpr float N2L2E = -2.8853900817779268f;   // -2*log2(e)

union FragU { bf16x8 v; unsigned u[4]; };

DEV unsigned cvtpk(float lo, float hi) {
  unsigned r;
  asm("v_cvt_pk_bf16_f32 %0, %1, %2" : "=v"(r) : "v"(lo), "v"(hi));
  return r;
}
DEV float pklo(unsigned u) { return __uint_as_float(u << 16); }
DEV float pkhi(unsigned u) { return __uint_as_float(u & 0xffff0000u); }

DEV f32x4 MFMA(FragU a, FragU b, f32x4 c) {
  return __builtin_amdgcn_mfma_f32_16x16x32_bf16(a.v, b.v, c, 0, 0, 0);
}

// One LSTM layer; one direction per blockIdx.y; one wave = 16 sequences.
// A-frag row (lane&15) = seq; B/C column (lane&15) = gate-row j.
// K=32 split into two 16-slot sections (q<2 -> sec0, q>=2 -> sec1).
// h kept in LDS as three bf16 component planes (pre-packed frag dwords);
// slot 14,15 of hc1 is constant 1.0 -> bias rides in B at those slots.
// Weights pre-scaled by -log2e (-2log2e for the g gate) so activations
// use exp2 directly.
// INM: 0 = fp32 x, IN=13 (layer1) ; 1 = bf16 hi/lo x, IN=28 (layers 2,3)
// OUTM: 0 = bf16 hi/lo y (28ch)   ; 1 = fp32 y (14ch, layer3)
template <int INM, int OUTM>
__global__ __launch_bounds__(256, 2) void lstm_k(
    const float* __restrict__ xf,
    const unsigned short* __restrict__ xhi,
    const unsigned short* __restrict__ xlo,
    const float* __restrict__ wihF, const float* __restrict__ whhF,
    const float* __restrict__ bihF, const float* __restrict__ bhhF,
    const float* __restrict__ wihB, const float* __restrict__ whhB,
    const float* __restrict__ bihB, const float* __restrict__ bhhB,
    unsigned short* __restrict__ yhi, unsigned short* __restrict__ ylo,
    float* __restrict__ yf)
{
  constexpr int IN = (INM == 0) ? 13 : 28;
  const int dir = (OUTM == 1) ? 0 : blockIdx.y;
  const float* __restrict__ wih = dir ? wihB : wihF;
  const float* __restrict__ whh = dir ? whhB : whhF;
  const float* __restrict__ bih = dir ? bihB : bihF;
  const float* __restrict__ bhh = dir ? bhhB : bhhF;

  const int tid = threadIdx.x;
  const int w = tid >> 6, lane = tid & 63;
  const int col = lane & 15, q = lane >> 4;
  const int qodd = q & 1, qhi = q >> 1;
  const bool jv = col < H;
  const int jc = jv ? col : 13;

  // per (wave, seq): hc1[8] | hc2[8] | hc3[8] | pad[4]  (dwords, stride 28)
  __shared__ unsigned hlds[4][16][28];
  {
    unsigned* hb = &hlds[w][0][0];
    for (int i = lane; i < 448; i += 64) hb[i] = ((i % 28) == 7) ? 0x3F803F80u : 0u;
  }

  // ---------------- B fragments (built once, pre-scaled) ----------------
  FragU Bx1[4], Bx2[4], Bh1[4], Bh2[4], Bh3[4];
#pragma unroll
  for (int g = 0; g < 4; ++g) {
    const int grow = g * H + jc;
    const float sc = (g == 2) ? N2L2E : NL2E;
    const float bsc = (bih[grow] + bhh[grow]) * sc;
    const unsigned bq1 = cvtpk(bsc, bsc);
    const float br1 = bsc - pklo(bq1);
    const unsigned bq2 = cvtpk(br1, br1);
    const float br2 = br1 - pklo(bq2);
    const unsigned bP12 = cvtpk(bsc, br1);   // (b1, b2)
    const unsigned bP30 = cvtpk(br2, 0.f);   // (b3, 0)
    const float* __restrict__ wr = wih + grow * IN;
    const float* __restrict__ ur = whh + grow * H;
#pragma unroll
    for (int p = 0; p < 4; ++p) {
      {  // x weights
        int l0; bool va, vb;
        if (INM == 0) {
          l0 = 8 * qodd + 2 * p;
          va = jv && (l0 < 13); vb = jv && (l0 + 1 < 13);
        } else {
          l0 = q * 8 - ((q == 3) ? 4 : 0) + 2 * p;
          const bool alive = !(q == 3 && p < 2);
          va = jv && alive; vb = va;
        }
        const float wa = va ? wr[l0] * sc : 0.f;
        const float wb = vb ? wr[l0 + 1] * sc : 0.f;
        const unsigned c1 = cvtpk(wa, wb);
        const float ra = wa - pklo(c1), rb = wb - pkhi(c1);
        const unsigned c2 = cvtpk(ra, rb);
        Bx1[g].u[p] = c1;
        Bx2[g].u[p] = (INM == 0 && qhi) ? 0u : c2;  // L1: sec1 of Bx2 = 0
      }
      {  // h weights: Bh1=[U1|U1](+b1,b2), Bh2=[U2|U2](+b3), Bh3=[U3|U1]
        const int m0 = 8 * qodd + 2 * p;
        const float ua = (jv && m0 < 14) ? ur[m0] * sc : 0.f;
        const float ub = (jv && (m0 + 1) < 14) ? ur[m0 + 1] * sc : 0.f;
        const unsigned c1 = cvtpk(ua, ub);
        const float ra = ua - pklo(c1), rb = ub - pkhi(c1);
        const unsigned c2 = cvtpk(ra, rb);
        const float ra2 = ra - pklo(c2), rb2 = rb - pkhi(c2);
        const unsigned c3 = cvtpk(ra2, rb2);
        unsigned h1 = c1, h2 = c2, h3 = qhi ? c1 : c3;
        if (q == 1 && p == 3) {  // sec0 slots 14,15: bias carriers (A = 1.0)
          h1 = jv ? bP12 : 0u; h2 = jv ? bP30 : 0u; h3 = 0u;
        }
        Bh1[g].u[p] = h1; Bh2[g].u[p] = h2; Bh3[g].u[p] = h3;
      }
    }
  }

  const long sb = (long)blockIdx.x * 64 + w * 16;
  const long arow = sb + col;  // this lane's seq for the A side

  // static LDS read pointers (Ah12: hc1/hc2 ; Ah13: hc1/hc3)
  const unsigned hbase = (unsigned)((w * 16 + col) * 28);
  const uint4* __restrict__ rp12 =
      (const uint4*)(&hlds[0][0][0] + hbase + (qhi ? 8 : 0) + qodd * 4);
  const uint4* __restrict__ rp13 =
      (const uint4*)(&hlds[0][0][0] + hbase + (qhi ? 16 : 0) + qodd * 4);

  // static LDS write pointers (one per owned seq)
  unsigned short* hw[4];
#pragma unroll
  for (int i = 0; i < 4; ++i)
    hw[i] = (unsigned short*)(&hlds[w][4 * q + i][0]) + col;

  constexpr int ROWX = (INM == 0) ? 52 : 56;
  const int t0 = dir ? T - 1 : 0;
  const int dsx = dir ? -ROWX : ROWX;
  const int dsy = dir ? -56 : 56;
  unsigned voffx = (unsigned)((arow * T + t0) * ROWX) +
                   (unsigned)(INM == 0 ? qodd * 32 : q * 16 - ((q == 3) ? 8 : 0));
  unsigned yoff[4];
#pragma unroll
  for (int i = 0; i < 4; ++i) {
    const long srow = sb + 4 * q + i;
    yoff[i] = (unsigned)((srow * T + t0) * 56) +
              (unsigned)((OUTM == 0) ? (dir * H + col) * 2 : col * 4);
  }

  float cc[4] = {0.f, 0.f, 0.f, 0.f};

  auto loadf = [&](float (&dst)[8], unsigned off) {
    const float* pa = (const float*)((const char*)xf + off);
    if (!qodd) {
#pragma unroll
      for (int e = 0; e < 8; ++e) dst[e] = pa[e];
    } else {  // l = 8..12 valid; clamp tail (B-side zeros kill the clones)
#pragma unroll
      for (int e = 0; e < 5; ++e) dst[e] = pa[e];
      dst[5] = dst[6] = dst[7] = dst[4];
    }
  };
  auto loadu = [&](unsigned (&dst)[8], unsigned off) {
    const char* bh = (const char*)xhi + off;
    const char* bl = (const char*)xlo + off;
    const uint2 a0 = *(const uint2*)bh;
    const uint2 a1 = *(const uint2*)(bh + 8);
    const uint2 b0 = *(const uint2*)bl;
    const uint2 b1 = *(const uint2*)(bl + 8);
    dst[0] = a0.x; dst[1] = a0.y; dst[2] = a1.x; dst[3] = a1.y;
    dst[4] = b0.x; dst[5] = b0.y; dst[6] = b1.x; dst[7] = b1.y;
  };

  auto STEP = [&](float (&xfb)[8], unsigned (&xub)[8]) {
    // h fragments straight from LDS (pre-packed components)
    FragU A12, A13;
    { const uint4 t4 = *rp12; A12.u[0]=t4.x; A12.u[1]=t4.y; A12.u[2]=t4.z; A12.u[3]=t4.w; }
    { const uint4 t4 = *rp13; A13.u[0]=t4.x; A13.u[1]=t4.y; A13.u[2]=t4.z; A13.u[3]=t4.w; }
    // x fragments
    FragU Ax1, Ax2;
    if constexpr (INM == 0) {
      unsigned c[4];
#pragma unroll
      for (int p = 0; p < 4; ++p) c[p] = cvtpk(xfb[2 * p], xfb[2 * p + 1]);
      if (qhi) {  // sec1 lanes carry the residual component
#pragma unroll
        for (int p = 0; p < 4; ++p) {
          const float ra = xfb[2 * p] - pklo(c[p]);
          const float rb = xfb[2 * p + 1] - pkhi(c[p]);
          c[p] = cvtpk(ra, rb);
        }
      }
#pragma unroll
      for (int p = 0; p < 4; ++p) Ax1.u[p] = c[p];
    } else {
#pragma unroll
      for (int p = 0; p < 4; ++p) { Ax1.u[p] = xub[p]; Ax2.u[p] = xub[4 + p]; }
    }
    // MFMAs
    f32x4 acc[4];
#pragma unroll
    for (int g = 0; g < 4; ++g) {
      f32x4 a = {0.f, 0.f, 0.f, 0.f};
      a = MFMA(Ax1, Bx1[g], a);          // x1W1 (+x2W1 for L1)
      if constexpr (INM == 0) {
        a = MFMA(Ax1, Bx2[g], a);        // x1W2
      } else {
        a = MFMA(Ax2, Bx1[g], a);        // x2W1
        a = MFMA(Ax1, Bx2[g], a);        // x1W2
      }
      a = MFMA(A12, Bh1[g], a);          // h1U1 + h2U1 + b1 + b2
      a = MFMA(A12, Bh2[g], a);          // h1U2 + h2U2 + b3
      a = MFMA(A13, Bh3[g], a);          // h1U3 + h3U1
      acc[g] = a;
    }
    // activations (weights pre-scaled: z' = -log2e*z ; g: -2log2e*z)
#pragma unroll
    for (int i = 0; i < 4; ++i) {
      const float zi = acc[0][i], zf = acc[1][i], zg = acc[2][i], zo = acc[3][i];
      const float Ei = __builtin_amdgcn_exp2f(zi);
      const float Ef = __builtin_amdgcn_exp2f(zf);
      const float Eo = __builtin_amdgcn_exp2f(zo);
      const float Eg = __builtin_amdgcn_exp2f(-fabsf(zg));
      float u = (1.f - Eg) * __builtin_amdgcn_rcpf((1.f + Ei) * (1.f + Eg));
      u = copysignf(u, __uint_as_float(__float_as_uint(zg) ^ 0x80000000u));
      const float cn = fmaf(cc[i], __builtin_amdgcn_rcpf(1.f + Ef), u);
      cc[i] = cn;
      const float Ec = __builtin_amdgcn_exp2f(fabsf(cn) * N2L2E);
      float hn = (1.f - Ec) * __builtin_amdgcn_rcpf((1.f + Eo) * (1.f + Ec));
      hn = copysignf(hn, cn);
      // 3-way split of h, written as bf16 components
      const unsigned c1 = cvtpk(hn, hn);
      const float r1 = hn - pklo(c1);
      const unsigned c2 = cvtpk(r1, r1);
      const float r2 = r1 - pklo(c2);
      const unsigned c3 = cvtpk(r2, r2);
      if (jv) {
        hw[i][0]  = (unsigned short)c1;
        hw[i][16] = (unsigned short)c2;
        hw[i][32] = (unsigned short)c3;
        if constexpr (OUTM == 0) {
          *(unsigned short*)((char*)yhi + yoff[i]) = (unsigned short)c1;
          *(unsigned short*)((char*)ylo + yoff[i]) = (unsigned short)c2;
        } else {
          *(float*)((char*)yf + yoff[i]) = hn;
        }
      }
      yoff[i] += dsy;
    }
  };

  float bufAf[8], bufBf[8];
  unsigned bufAu[8], bufBu[8];
  if constexpr (INM == 0) loadf(bufAf, voffx); else loadu(bufAu, voffx);
#pragma unroll 1
  for (int s = 0; s < T; s += 2) {
    const unsigned vb = voffx + (unsigned)dsx;
    if constexpr (INM == 0) loadf(bufBf, vb); else loadu(bufBu, vb);
    STEP(bufAf, bufAu);
    const unsigned va = (s + 2 < T) ? vb + (unsigned)dsx : vb;
    if constexpr (INM == 0) loadf(bufAf, va); else loadu(bufAu, va);
    STEP(bufBf, bufBu);
    voffx = va;
  }
}

extern "C" void kernel_launch(void* const* d_in, const int* in_sizes, int n_in,
                              void* d_out, int out_size, void* d_ws, size_t ws_size,
                              hipStream_t stream) {
  const float* x     = (const float*)d_in[0];
  const float* wih1f = (const float*)d_in[1];
  const float* whh1f = (const float*)d_in[2];
  const float* bih1f = (const float*)d_in[3];
  const float* bhh1f = (const float*)d_in[4];
  const float* wih1b = (const float*)d_in[5];
  const float* whh1b = (const float*)d_in[6];
  const float* bih1b = (const float*)d_in[7];
  const float* bhh1b = (const float*)d_in[8];
  const float* wih2f = (const float*)d_in[9];
  const float* whh2f = (const float*)d_in[10];
  const float* bih2f = (const float*)d_in[11];
  const float* bhh2f = (const float*)d_in[12];
  const float* wih2b = (const float*)d_in[13];
  const float* whh2b = (const float*)d_in[14];
  const float* bih2b = (const float*)d_in[15];
  const float* bhh2b = (const float*)d_in[16];
  const float* wih3  = (const float*)d_in[17];
  const float* whh3  = (const float*)d_in[18];
  const float* bih3  = (const float*)d_in[19];
  const float* bhh3  = (const float*)d_in[20];

  using usp = unsigned short*;
  const size_t NSEQT = (size_t)BATCH * T;  // 1,048,576 rows
  usp y1hi = (usp)d_ws;
  usp y1lo = y1hi + NSEQT * 28;
  usp y2hi = y1lo + NSEQT * 28;
  usp y2lo = y2hi + NSEQT * 28;
  float* out = (float*)d_out;

  const dim3 blk(256);
  const dim3 grid_bi(BATCH / 64, 2);
  const dim3 grid_uni(BATCH / 64, 1);

  lstm_k<0, 0><<<grid_bi, blk, 0, stream>>>(
      x, nullptr, nullptr,
      wih1f, whh1f, bih1f, bhh1f, wih1b, whh1b, bih1b, bhh1b,
      y1hi, y1lo, nullptr);
  lstm_k<1, 0><<<grid_bi, blk, 0, stream>>>(
      nullptr, y1hi, y1lo,
      wih2f, whh2f, bih2f, bhh2f, wih2b, whh2b, bih2b, bhh2b,
      y2hi, y2lo, nullptr);
  lstm_k<1, 1><<<grid_uni, blk, 0, stream>>>(
      nullptr, y2hi, y2lo,
      wih3, whh3, bih3, bhh3, wih3, whh3, bih3, bhh3,
      nullptr, nullptr, out);
}

// Round 5
// 332.148 us; speedup vs baseline: 1.1424x; 1.1424x over previous
//
#include <hip/hip_runtime.h>

#define DEV __device__ __forceinline__

typedef short bf16x8 __attribute__((ext_vector_type(8)));
typedef float f32x4 __attribute__((ext_vector_type(4)));

constexpr int BATCH = 16384, T = 64, H = 14;
constexpr float NL2E  = -1.4426950408889634f;   // -log2(e)
constexpr float N2L2E = -2.8853900817779268f;   // -2*log2(e)

union FragU { bf16x8 v; unsigned u[4]; };

DEV unsigned cvtpk(float lo, float hi) {
  unsigned r;
  asm("v_cvt_pk_bf16_f32 %0, %1, %2" : "=v"(r) : "v"(lo), "v"(hi));
  return r;
}
DEV float pklo(unsigned u) { return __uint_as_float(u << 16); }
DEV float pkhi(unsigned u) { return __uint_as_float(u & 0xffff0000u); }

DEV f32x4 MFMA(FragU a, FragU b, f32x4 c) {
  return __builtin_amdgcn_mfma_f32_16x16x32_bf16(a.v, b.v, c, 0, 0, 0);
}

// One LSTM layer; one direction per blockIdx.y; one wave = 16 sequences.
// Inter-layer tensors are direction-de-interleaved bf16 hi/lo planes with
// rows padded to 16 ch (32B): [seq][t][16]. All global writes are staged in
// LDS and flushed every 16 steps as full-cache-line dwordx4 bursts.
// k-layout (IN=28): sec0 (q<2) = fwd plane ch 0..15, sec1 (q>=2) = bwd plane.
// h in LDS as three bf16 component planes; bias rides B at hc1 slots 14,15
// against constant-1.0 LDS pads. Weights pre-scaled by -log2e (-2log2e for g).
// INM: 0 = fp32 x [seq][t][13] (layer1) ; 1 = bf16 4-plane x (layers 2,3)
// OUTM: 0 = bf16 4-plane y ; 1 = fp32 y [seq][t][14] (layer 3)
template <int INM, int OUTM>
__global__ __launch_bounds__(256, 2) void lstm_k(
    const float* __restrict__ xf,
    const unsigned short* __restrict__ xfh, const unsigned short* __restrict__ xfl,
    const unsigned short* __restrict__ xbh, const unsigned short* __restrict__ xbl,
    const float* __restrict__ wihF, const float* __restrict__ whhF,
    const float* __restrict__ bihF, const float* __restrict__ bhhF,
    const float* __restrict__ wihB, const float* __restrict__ whhB,
    const float* __restrict__ bihB, const float* __restrict__ bhhB,
    unsigned short* __restrict__ yFh, unsigned short* __restrict__ yFl,
    unsigned short* __restrict__ yBh, unsigned short* __restrict__ yBl,
    float* __restrict__ yf)
{
  constexpr int IN = (INM == 0) ? 13 : 28;
  const int dir = (OUTM == 1) ? 0 : blockIdx.y;
  const float* __restrict__ wih = dir ? wihB : wihF;
  const float* __restrict__ whh = dir ? whhB : whhF;
  const float* __restrict__ bih = dir ? bihB : bihF;
  const float* __restrict__ bhh = dir ? bhhB : bhhF;
  unsigned short* __restrict__ yhiP = dir ? yBh : yFh;
  unsigned short* __restrict__ yloP = dir ? yBl : yFl;

  const int tid = threadIdx.x;
  const int w = tid >> 6, lane = tid & 63;
  const int col = lane & 15, q = lane >> 4;
  const int qodd = q & 1, qhi = q >> 1;
  const bool jv = col < H;
  const int jc = jv ? col : 13;

  // per (wave, seq): hc1[8] | hc2[8] | hc3[8] | pad[4]  (dwords, stride 28)
  __shared__ unsigned hlds[4][16][28];                // 7168 B
  // y stage: [wave][plane][t&15][seq][16ch] bf16 (OUTM1 reuses as float stage)
  __shared__ __align__(16) unsigned short yst[4][2][16][16][16];  // 32768 B
  float* __restrict__ fst = (float*)&yst[w][0][0][0][0];  // [16][16][16] f32
  {
    unsigned* hb = &hlds[w][0][0];
    for (int i = lane; i < 448; i += 64) hb[i] = ((i % 28) == 7) ? 0x3F803F80u : 0u;
  }

  // ---------------- B fragments (built once, pre-scaled) ----------------
  FragU Bx1[4], Bx2[4], Bh1[4], Bh2[4], Bh3[4];
#pragma unroll
  for (int g = 0; g < 4; ++g) {
    const int grow = g * H + jc;
    const float sc = (g == 2) ? N2L2E : NL2E;
    const float bsc = (bih[grow] + bhh[grow]) * sc;
    const unsigned bq1 = cvtpk(bsc, bsc);
    const float br1 = bsc - pklo(bq1);
    const unsigned bq2 = cvtpk(br1, br1);
    const float br2 = br1 - pklo(bq2);
    const unsigned bP12 = cvtpk(bsc, br1);   // (b1, b2)
    const unsigned bP30 = cvtpk(br2, 0.f);   // (b3, 0)
    const float* __restrict__ wr = wih + grow * IN;
    const float* __restrict__ ur = whh + grow * H;
#pragma unroll
    for (int p = 0; p < 4; ++p) {
      {  // x weights
        float wa = 0.f, wb = 0.f;
        if (INM == 0) {  // 13 ch over sec0/sec1 value+residual scheme
          const int l0 = 8 * qodd + 2 * p;
          if (jv && l0 < 13) wa = wr[l0] * sc;
          if (jv && l0 + 1 < 13) wb = wr[l0 + 1] * sc;
        } else {         // plane-local ch l = 8*qodd+2p+s, wih col = qhi*14 + l
          const int l0 = 8 * qodd + 2 * p;
          if (jv && l0 < 14) wa = wr[qhi * 14 + l0] * sc;
          if (jv && l0 + 1 < 14) wb = wr[qhi * 14 + l0 + 1] * sc;
        }
        const unsigned c1 = cvtpk(wa, wb);
        const float ra = wa - pklo(c1), rb = wb - pkhi(c1);
        const unsigned c2 = cvtpk(ra, rb);
        Bx1[g].u[p] = c1;
        Bx2[g].u[p] = (INM == 0 && qhi) ? 0u : c2;  // L1: sec1 of Bx2 = 0
      }
      {  // h weights: Bh1=[U1|U1](+b1,b2), Bh2=[U2|U2](+b3), Bh3=[U3|U1]
        const int m0 = 8 * qodd + 2 * p;
        const float ua = (jv && m0 < 14) ? ur[m0] * sc : 0.f;
        const float ub = (jv && (m0 + 1) < 14) ? ur[m0 + 1] * sc : 0.f;
        const unsigned c1 = cvtpk(ua, ub);
        const float ra = ua - pklo(c1), rb = ub - pkhi(c1);
        const unsigned c2 = cvtpk(ra, rb);
        const float ra2 = ra - pklo(c2), rb2 = rb - pkhi(c2);
        const unsigned c3 = cvtpk(ra2, rb2);
        unsigned h1 = c1, h2 = c2, h3 = qhi ? c1 : c3;
        if (q == 1 && p == 3) {  // sec0 slots 14,15: bias carriers (A = 1.0)
          h1 = jv ? bP12 : 0u; h2 = jv ? bP30 : 0u; h3 = 0u;
        }
        Bh1[g].u[p] = h1; Bh2[g].u[p] = h2; Bh3[g].u[p] = h3;
      }
    }
  }

  const long sb = (long)blockIdx.x * 64 + w * 16;
  const long arow = sb + col;  // this lane's seq for the A side

  // static LDS read pointers (Ah12: hc1/hc2 ; Ah13: hc1/hc3)
  const unsigned hbase = (unsigned)((w * 16 + col) * 28);
  const uint4* __restrict__ rp12 =
      (const uint4*)(&hlds[0][0][0] + hbase + (qhi ? 8 : 0) + qodd * 4);
  const uint4* __restrict__ rp13 =
      (const uint4*)(&hlds[0][0][0] + hbase + (qhi ? 16 : 0) + qodd * 4);

  // static LDS write pointers for h (one per owned seq)
  unsigned short* hw[4];
#pragma unroll
  for (int i = 0; i < 4; ++i)
    hw[i] = (unsigned short*)(&hlds[w][4 * q + i][0]) + col;

  const int t0 = dir ? T - 1 : 0;
  constexpr int ROWX = (INM == 0) ? 52 : 32;  // bytes per x row (per plane)
  const int dsx = dir ? -ROWX : ROWX;
  unsigned voffx = (unsigned)((arow * T + t0) * ROWX) +
                   (unsigned)(INM == 0 ? qodd * 32 : qodd * 16);
  const unsigned short* __restrict__ xph = (INM == 0) ? nullptr : (qhi ? xbh : xfh);
  const unsigned short* __restrict__ xpl = (INM == 0) ? nullptr : (qhi ? xbl : xfl);

  float cc[4] = {0.f, 0.f, 0.f, 0.f};

  auto loadf = [&](float (&dst)[8], unsigned off) {
    const float* pa = (const float*)((const char*)xf + off);
    if (!qodd) {
#pragma unroll
      for (int e = 0; e < 8; ++e) dst[e] = pa[e];
    } else {  // l = 8..12 valid; clamp tail (B-side zeros kill the clones)
#pragma unroll
      for (int e = 0; e < 5; ++e) dst[e] = pa[e];
      dst[5] = dst[6] = dst[7] = dst[4];
    }
  };
  auto loadu = [&](unsigned (&dst)[8], unsigned off) {
    const uint4 a = *(const uint4*)((const char*)xph + off);
    const uint4 b = *(const uint4*)((const char*)xpl + off);
    dst[0] = a.x; dst[1] = a.y; dst[2] = a.z; dst[3] = a.w;
    dst[4] = b.x; dst[5] = b.y; dst[6] = b.z; dst[7] = b.w;
  };

  auto STEP = [&](int t, float (&xfb)[8], unsigned (&xub)[8]) {
    // h fragments straight from LDS (pre-packed components)
    FragU A12, A13;
    { const uint4 t4 = *rp12; A12.u[0]=t4.x; A12.u[1]=t4.y; A12.u[2]=t4.z; A12.u[3]=t4.w; }
    { const uint4 t4 = *rp13; A13.u[0]=t4.x; A13.u[1]=t4.y; A13.u[2]=t4.z; A13.u[3]=t4.w; }
    // x fragments
    FragU Ax1, Ax2;
    if constexpr (INM == 0) {
      unsigned c[4];
#pragma unroll
      for (int p = 0; p < 4; ++p) c[p] = cvtpk(xfb[2 * p], xfb[2 * p + 1]);
      if (qhi) {  // sec1 lanes carry the residual component
#pragma unroll
        for (int p = 0; p < 4; ++p) {
          const float ra = xfb[2 * p] - pklo(c[p]);
          const float rb = xfb[2 * p + 1] - pkhi(c[p]);
          c[p] = cvtpk(ra, rb);
        }
      }
#pragma unroll
      for (int p = 0; p < 4; ++p) Ax1.u[p] = c[p];
    } else {
#pragma unroll
      for (int p = 0; p < 4; ++p) { Ax1.u[p] = xub[p]; Ax2.u[p] = xub[4 + p]; }
    }
    // MFMAs
    f32x4 acc[4];
#pragma unroll
    for (int g = 0; g < 4; ++g) {
      f32x4 a = {0.f, 0.f, 0.f, 0.f};
      a = MFMA(Ax1, Bx1[g], a);          // x1W1 (+x2W1 for L1)
      if constexpr (INM == 0) {
        a = MFMA(Ax1, Bx2[g], a);        // x1W2
      } else {
        a = MFMA(Ax2, Bx1[g], a);        // x2W1
        a = MFMA(Ax1, Bx2[g], a);        // x1W2
      }
      a = MFMA(A12, Bh1[g], a);          // h1U1 + h2U1 + b1 + b2
      a = MFMA(A12, Bh2[g], a);          // h1U2 + h2U2 + b3
      a = MFMA(A13, Bh3[g], a);          // h1U3 + h3U1
      acc[g] = a;
    }
    // activations (weights pre-scaled: z' = -log2e*z ; g: -2log2e*z)
    const int ts = t & 15;
#pragma unroll
    for (int i = 0; i < 4; ++i) {
      const float zi = acc[0][i], zf = acc[1][i], zg = acc[2][i], zo = acc[3][i];
      const float Ei = __builtin_amdgcn_exp2f(zi);
      const float Ef = __builtin_amdgcn_exp2f(zf);
      const float Eo = __builtin_amdgcn_exp2f(zo);
      const float Eg = __builtin_amdgcn_exp2f(-fabsf(zg));
      float u = (1.f - Eg) * __builtin_amdgcn_rcpf((1.f + Ei) * (1.f + Eg));
      u = copysignf(u, __uint_as_float(__float_as_uint(zg) ^ 0x80000000u));
      const float cn = fmaf(cc[i], __builtin_amdgcn_rcpf(1.f + Ef), u);
      cc[i] = cn;
      const float Ec = __builtin_amdgcn_exp2f(fabsf(cn) * N2L2E);
      float hn = (1.f - Ec) * __builtin_amdgcn_rcpf((1.f + Eo) * (1.f + Ec));
      hn = copysignf(hn, cn);
      // 3-way split of h -> bf16 components
      const unsigned c1 = cvtpk(hn, hn);
      const float r1 = hn - pklo(c1);
      const unsigned c2 = cvtpk(r1, r1);
      const float r2 = r1 - pklo(c2);
      const unsigned c3 = cvtpk(r2, r2);
      if (jv) {
        hw[i][0]  = (unsigned short)c1;
        hw[i][16] = (unsigned short)c2;
        hw[i][32] = (unsigned short)c3;
        if constexpr (OUTM == 0) {
          yst[w][0][ts][4 * q + i][col] = (unsigned short)c1;
          yst[w][1][ts][4 * q + i][col] = (unsigned short)c2;
        } else {
          fst[(ts * 16 + 4 * q + i) * 16 + col] = hn;
        }
      } else if (OUTM == 0) {  // zero the pad channels (MFMA 0*NaN guard)
        yst[w][0][ts][4 * q + i][col] = 0;
        yst[w][1][ts][4 * q + i][col] = 0;
      }
    }
  };

  const int sq = lane >> 2, part = lane & 3;  // flush roles
  auto flushY = [&](int tbase) {  // OUTM==0: 512B/seq/plane, full lines
    const unsigned gbyte =
        (((unsigned)(sb + sq) * T + (unsigned)tbase) * 16u + part * 64u) * 2u;
#pragma unroll
    for (int pl = 0; pl < 2; ++pl) {
      char* gp = (char*)(pl ? yloP : yhiP) + gbyte;
#pragma unroll
      for (int tt = 0; tt < 4; ++tt) {
        const uint4 v0 = *(const uint4*)&yst[w][pl][4 * part + tt][sq][0];
        const uint4 v1 = *(const uint4*)&yst[w][pl][4 * part + tt][sq][8];
        *(uint4*)(gp + tt * 32) = v0;
        *(uint4*)(gp + tt * 32 + 16) = v1;
      }
    }
  };
  auto flushO = [&](int tbase) {  // OUTM==1: 896B/seq, full lines
    union { float f[56]; uint4 v[14]; } ub;
#pragma unroll
    for (int tt = 0; tt < 4; ++tt) {
      const float* r = fst + ((4 * part + tt) * 16 + sq) * 16;
      const float4 a0 = *(const float4*)(r);
      const float4 a1 = *(const float4*)(r + 4);
      const float4 a2 = *(const float4*)(r + 8);
      const float2 a3 = *(const float2*)(r + 12);
      const int o = tt * 14;
      ub.f[o+0]=a0.x; ub.f[o+1]=a0.y; ub.f[o+2]=a0.z; ub.f[o+3]=a0.w;
      ub.f[o+4]=a1.x; ub.f[o+5]=a1.y; ub.f[o+6]=a1.z; ub.f[o+7]=a1.w;
      ub.f[o+8]=a2.x; ub.f[o+9]=a2.y; ub.f[o+10]=a2.z; ub.f[o+11]=a2.w;
      ub.f[o+12]=a3.x; ub.f[o+13]=a3.y;
    }
    char* gp = (char*)yf +
               (((unsigned)(sb + sq) * T + (unsigned)tbase) * 14u + part * 56u) * 4u;
#pragma unroll
    for (int m = 0; m < 14; ++m) *(uint4*)(gp + m * 16) = ub.v[m];
  };

  float bufAf[8], bufBf[8];
  unsigned bufAu[8], bufBu[8];
  if constexpr (INM == 0) loadf(bufAf, voffx); else loadu(bufAu, voffx);
#pragma unroll 1
  for (int s = 0; s < T; s += 2) {
    const int ta = dir ? T - 1 - s : s;
    const int tb = dir ? T - 2 - s : s + 1;
    const unsigned vb = voffx + (unsigned)dsx;
    if constexpr (INM == 0) loadf(bufBf, vb); else loadu(bufBu, vb);
    STEP(ta, bufAf, bufAu);
    const unsigned va = (s + 2 < T) ? vb + (unsigned)dsx : vb;
    if constexpr (INM == 0) loadf(bufAf, va); else loadu(bufAu, va);
    STEP(tb, bufBf, bufBu);
    voffx = va;
    if ((s & 15) == 14) {
      const int tbase = tb & ~15;
      if constexpr (OUTM == 0) flushY(tbase); else flushO(tbase);
    }
  }
}

extern "C" void kernel_launch(void* const* d_in, const int* in_sizes, int n_in,
                              void* d_out, int out_size, void* d_ws, size_t ws_size,
                              hipStream_t stream) {
  const float* x     = (const float*)d_in[0];
  const float* wih1f = (const float*)d_in[1];
  const float* whh1f = (const float*)d_in[2];
  const float* bih1f = (const float*)d_in[3];
  const float* bhh1f = (const float*)d_in[4];
  const float* wih1b = (const float*)d_in[5];
  const float* whh1b = (const float*)d_in[6];
  const float* bih1b = (const float*)d_in[7];
  const float* bhh1b = (const float*)d_in[8];
  const float* wih2f = (const float*)d_in[9];
  const float* whh2f = (const float*)d_in[10];
  const float* bih2f = (const float*)d_in[11];
  const float* bhh2f = (const float*)d_in[12];
  const float* wih2b = (const float*)d_in[13];
  const float* whh2b = (const float*)d_in[14];
  const float* bih2b = (const float*)d_in[15];
  const float* bhh2b = (const float*)d_in[16];
  const float* wih3  = (const float*)d_in[17];
  const float* whh3  = (const float*)d_in[18];
  const float* bih3  = (const float*)d_in[19];
  const float* bhh3  = (const float*)d_in[20];

  using usp = unsigned short*;
  const size_t PL = (size_t)BATCH * T * 16;  // ushorts per plane (padded 16ch)
  usp y1fh = (usp)d_ws;
  usp y1fl = y1fh + PL;
  usp y1bh = y1fl + PL;
  usp y1bl = y1bh + PL;
  usp y2fh = y1bl + PL;
  usp y2fl = y2fh + PL;
  usp y2bh = y2fl + PL;
  usp y2bl = y2bh + PL;
  float* out = (float*)d_out;

  const dim3 blk(256);
  const dim3 grid_bi(BATCH / 64, 2);
  const dim3 grid_uni(BATCH / 64, 1);

  lstm_k<0, 0><<<grid_bi, blk, 0, stream>>>(
      x, nullptr, nullptr, nullptr, nullptr,
      wih1f, whh1f, bih1f, bhh1f, wih1b, whh1b, bih1b, bhh1b,
      y1fh, y1fl, y1bh, y1bl, nullptr);
  lstm_k<1, 0><<<grid_bi, blk, 0, stream>>>(
      nullptr, y1fh, y1fl, y1bh, y1bl,
      wih2f, whh2f, bih2f, bhh2f, wih2b, whh2b, bih2b, bhh2b,
      y2fh, y2fl, y2bh, y2bl, nullptr);
  lstm_k<1, 1><<<grid_uni, blk, 0, stream>>>(
      nullptr, y2fh, y2fl, y2bh, y2bl,
      wih3, whh3, bih3, bhh3, wih3, whh3, bih3, bhh3,
      nullptr, nullptr, nullptr, nullptr, out);
}